// Round 1
// baseline (297.241 us; speedup 1.0000x reference)
//
#include <hip/hip_runtime.h>

#define NTOK 16384
#define CD   256
#define NH   8
#define HD   32

typedef __attribute__((ext_vector_type(4))) float f32x4;
typedef __attribute__((ext_vector_type(8))) short s16x8;

__device__ __forceinline__ unsigned short f2bf(float x) {
  union { float f; unsigned u; } a; a.f = x;
  unsigned r = a.u + 0x7fffu + ((a.u >> 16) & 1u);
  return (unsigned short)(r >> 16);
}
__device__ __forceinline__ float bf2f(unsigned short b) {
  union { unsigned u; float f; } a; a.u = ((unsigned)b) << 16;
  return a.f;
}

// ---------------------------------------------------------------------------
// Kernel 1: per-(stream,batch) Gram matrices  G = inp^T inp  [256x256] f32.
// 256 blocks = 8 matrices x 32 chunks of 512 rows. 512 threads (8 waves).
// f32 -> bf16 hi+lo split; accumulate hi^T hi + lo^T hi + hi^T lo via MFMA.
// LDS tile: [256 cols][128 k] bf16 (k = 64 hi rows then 64 lo rows),
// XOR-swizzled at 8-element-octet granularity for conflict-free b128 access.
// ---------------------------------------------------------------------------
__global__ __launch_bounds__(512) void gram_kernel(
    const float* __restrict__ rgb, const float* __restrict__ xin,
    float* __restrict__ Gout)
{
  __shared__ unsigned short lds[2][CD * 128];

  const int bid   = blockIdx.x;
  const int mat   = bid >> 5;            // 0..7 : s*4 + b
  const int chunk = bid & 31;
  const float* __restrict__ src =
      (mat < 4 ? rgb : xin) + (size_t)(mat & 3) * (NTOK * CD) + (size_t)chunk * 512 * CD;
  float* __restrict__ G = Gout + (size_t)mat * (CD * CD);

  const int t    = threadIdx.x;
  const int lane = t & 63;
  const int wv   = t >> 6;               // wave 0..7
  const int wr   = wv >> 2;              // M block (0..1) -> rows 128*wr
  const int wc   = wv & 3;               // N block (0..3) -> cols 64*wc
  const int cm   = lane & 15;
  const int qq   = lane >> 4;

  f32x4 acc[8][4];
#pragma unroll
  for (int i = 0; i < 8; ++i)
#pragma unroll
    for (int j = 0; j < 4; ++j) acc[i][j] = (f32x4){0.f, 0.f, 0.f, 0.f};

  f32x4 v[8];

  auto issue_loads = [&](int step) {
    const f32x4* p = (const f32x4*)(src + (size_t)step * 64 * CD);
#pragma unroll
    for (int i = 0; i < 8; ++i)
      v[i] = p[(wv * 8 + i) * (CD / 4) + lane];   // row wv*8+i, cols lane*4..+3
  };

  auto stage = [&](int buf) {
#pragma unroll
    for (int j = 0; j < 4; ++j) {
      const int c = lane * 4 + j;
      const int s = (c ^ (c >> 3)) & 7;
      s16x8 hi8, lo8;
#pragma unroll
      for (int i = 0; i < 8; ++i) {
        float x = v[i][j];
        unsigned short hb = f2bf(x);
        unsigned short lb = f2bf(x - bf2f(hb));
        hi8[i] = (short)hb;
        lo8[i] = (short)lb;
      }
      unsigned short* base = &lds[buf][c * 128];
      const int off = ((wv ^ s) & 7) * 8;
      *(s16x8*)(base + off)      = hi8;   // octet o = wv      (hi half, k 0..63)
      *(s16x8*)(base + off + 64) = lo8;   // octet o = 8 + wv  (lo half, k 64..127)
    }
  };

  auto compute = [&](int buf) {
    const unsigned short* L = lds[buf];
    const int OA[6] = {0, 4, 8, 12, 0, 4};   // ks 0,1: hi.hi ; 2,3: lo.hi ; 4,5: hi.lo
    const int OB[6] = {0, 4, 0, 4, 8, 12};
#pragma unroll
    for (int ks = 0; ks < 6; ++ks) {
      s16x8 af[8], bfr[4];
#pragma unroll
      for (int mt = 0; mt < 8; ++mt) {
        const int c = wr * 128 + mt * 16 + cm;
        const int s = (c ^ (c >> 3)) & 7;
        const int o = OA[ks] + qq;
        const int slot = (o & 8) | ((o ^ s) & 7);
        af[mt] = *(const s16x8*)&L[c * 128 + slot * 8];
      }
#pragma unroll
      for (int nt = 0; nt < 4; ++nt) {
        const int c = wc * 64 + nt * 16 + cm;
        const int s = (c ^ (c >> 3)) & 7;
        const int o = OB[ks] + qq;
        const int slot = (o & 8) | ((o ^ s) & 7);
        bfr[nt] = *(const s16x8*)&L[c * 128 + slot * 8];
      }
#pragma unroll
      for (int mt = 0; mt < 8; ++mt)
#pragma unroll
        for (int nt = 0; nt < 4; ++nt)
          acc[mt][nt] = __builtin_amdgcn_mfma_f32_16x16x32_bf16(
              af[mt], bfr[nt], acc[mt][nt], 0, 0, 0);
    }
  };

  issue_loads(0);
  stage(0);
  __syncthreads();
#pragma unroll 2
  for (int step = 0; step < 8; ++step) {
    const int cur = step & 1;
    if (step + 1 < 8) issue_loads(step + 1);
    compute(cur);
    if (step + 1 < 8) {
      stage(cur ^ 1);
      __syncthreads();
    }
  }

  // accumulate partial Gram into global (f32 atomics)
#pragma unroll
  for (int mt = 0; mt < 8; ++mt)
#pragma unroll
    for (int nt = 0; nt < 4; ++nt)
#pragma unroll
      for (int r = 0; r < 4; ++r) {
        const int row = wr * 128 + mt * 16 + qq * 4 + r;
        const int col = wc * 64 + nt * 16 + cm;
        atomicAdd(&G[row * CD + col], acc[mt][nt][r]);
      }
}

// ---------------------------------------------------------------------------
// Kernel 2: ctxA = Wk_h @ G   [32 x 256] per (s,b,h); f32 VALU.
// grid 256 = (s*4+b)*32 + h*4 + cq ; block 256.
// ---------------------------------------------------------------------------
__global__ __launch_bounds__(256) void ctxa_kernel(
    const float* __restrict__ Wkv_rgb, const float* __restrict__ Wkv_x,
    const float* __restrict__ G, float* __restrict__ ctxA)
{
  const int bid = blockIdx.x;
  const int cq  = bid & 3;
  const int h   = (bid >> 2) & 7;
  const int mat = bid >> 5;              // s*4+b
  const int s   = mat >> 2;
  const int t   = threadIdx.x;
  const int d   = t >> 3;                // 0..31
  const int sub = t & 7;                 // 8 cols of 8

  const float* __restrict__ W  = (s == 0 ? Wkv_rgb : Wkv_x);
  const float* __restrict__ wk = W + (size_t)(h * HD + d) * CD;
  const float* __restrict__ g  = G + (size_t)mat * (CD * CD) + cq * 64 + sub * 8;

  f32x4 a0 = (f32x4){0.f,0.f,0.f,0.f}, a1 = (f32x4){0.f,0.f,0.f,0.f};
  for (int c = 0; c < CD; ++c) {
    const float w = wk[c];
    const f32x4* gr = (const f32x4*)(g + (size_t)c * CD);
    a0 += gr[0] * w;
    a1 += gr[1] * w;
  }
  float* outp = ctxA + ((size_t)(mat * NH + h) * HD + d) * CD + cq * 64 + sub * 8;
  *(f32x4*)outp       = a0;
  *(f32x4*)(outp + 4) = a1;
}

// ---------------------------------------------------------------------------
// Kernel 3: ctx = scale * ctxA @ Wv_h^T  [32 x 32], softmax over rows (d).
// grid 64 = mat*8 + h ; block 256.
// ---------------------------------------------------------------------------
__global__ __launch_bounds__(256) void ctxb_kernel(
    const float* __restrict__ Wkv_rgb, const float* __restrict__ Wkv_x,
    const float* __restrict__ ctxA, float* __restrict__ S)
{
  const int bid = blockIdx.x;            // mat*8 + h
  const int h   = bid & 7;
  const int mat = bid >> 3;
  const int s   = mat >> 2;
  const int t   = threadIdx.x;
  const int d   = t >> 3;                // 0..31
  const int eg  = t & 7;                 // 4 e's each

  __shared__ float sl[32 * 33];

  const float* __restrict__ W = (s == 0 ? Wkv_rgb : Wkv_x);
  const float* __restrict__ a = ctxA + ((size_t)bid * HD + d) * CD;

  float acc[4] = {0.f, 0.f, 0.f, 0.f};
  for (int c = 0; c < CD; ++c) {
    const float av = a[c];
#pragma unroll
    for (int j = 0; j < 4; ++j)
      acc[j] += av * W[(size_t)(CD + h * HD + eg * 4 + j) * CD + c];
  }
  const float scale = 0.17677669529663687f;   // 32^-0.5
#pragma unroll
  for (int j = 0; j < 4; ++j) sl[d * 33 + eg * 4 + j] = acc[j] * scale;
  __syncthreads();

  if (t < 32) {
    const int e = t;
    float m = -1e30f;
#pragma unroll
    for (int dd = 0; dd < 32; ++dd) m = fmaxf(m, sl[dd * 33 + e]);
    float ex[32];
    float sum = 0.f;
#pragma unroll
    for (int dd = 0; dd < 32; ++dd) { ex[dd] = __expf(sl[dd * 33 + e] - m); sum += ex[dd]; }
    const float inv = 1.f / sum;
    float* outp = S + (size_t)bid * (HD * HD);
#pragma unroll
    for (int dd = 0; dd < 32; ++dd) outp[dd * HD + e] = ex[dd] * inv;
  }
}

// ---------------------------------------------------------------------------
// Kernel 4: out_s = q_s @ blockdiag(S_{1-s})  — memory-bound bf16 MFMA pass.
// grid 4096 = ((s*4+b)*8 + h)*64 + nc ; block 256 (4 waves), 256 rows/block.
// ---------------------------------------------------------------------------
__global__ __launch_bounds__(256) void out_kernel(
    const float* __restrict__ rgb, const float* __restrict__ xin,
    const float* __restrict__ S, float* __restrict__ out)
{
  const int bid = blockIdx.x;
  const int nc  = bid & 63;
  const int h   = (bid >> 6) & 7;
  const int mat = bid >> 9;              // s*4 + b
  const int s   = mat >> 2;
  const int b   = mat & 3;

  const int t    = threadIdx.x;
  const int lane = t & 63;
  const int wv   = t >> 6;               // 0..3
  const int cm   = lane & 15;
  const int qq   = lane >> 4;

  const float* __restrict__ src = (s == 0 ? rgb : xin) + (size_t)b * NTOK * CD;
  float* __restrict__ dst = out + (size_t)s * (4ull * NTOK * CD) + (size_t)b * NTOK * CD;
  const float* __restrict__ sm =
      S + (size_t)(((1 - s) * 4 + b) * NH + h) * (HD * HD);

  // B fragments: ctx of the other stream, K=32, two 16-col tiles
  s16x8 bf0, bf1;
#pragma unroll
  for (int j = 0; j < 8; ++j) {
    const int k = qq * 8 + j;
    bf0[j] = (short)f2bf(sm[k * HD + cm]);
    bf1[j] = (short)f2bf(sm[k * HD + 16 + cm]);
  }

#pragma unroll
  for (int it = 0; it < 4; ++it) {
    const int row0 = nc * 256 + wv * 64 + it * 16;
    const float* qrow = src + (size_t)(row0 + cm) * CD + h * HD + qq * 8;
    const f32x4 q0 = *(const f32x4*)qrow;
    const f32x4 q1 = *(const f32x4*)(qrow + 4);
    s16x8 af;
#pragma unroll
    for (int j = 0; j < 4; ++j) {
      af[j]     = (short)f2bf(q0[j]);
      af[4 + j] = (short)f2bf(q1[j]);
    }
    f32x4 acc0 = (f32x4){0.f,0.f,0.f,0.f};
    f32x4 acc1 = (f32x4){0.f,0.f,0.f,0.f};
    acc0 = __builtin_amdgcn_mfma_f32_16x16x32_bf16(af, bf0, acc0, 0, 0, 0);
    acc1 = __builtin_amdgcn_mfma_f32_16x16x32_bf16(af, bf1, acc1, 0, 0, 0);
#pragma unroll
    for (int r = 0; r < 4; ++r) {
      const int row = row0 + qq * 4 + r;
      dst[(size_t)row * CD + h * HD + cm]      = acc0[r];
      dst[(size_t)row * CD + h * HD + 16 + cm] = acc1[r];
    }
  }
}

// ---------------------------------------------------------------------------
extern "C" void kernel_launch(void* const* d_in, const int* in_sizes, int n_in,
                              void* d_out, int out_size, void* d_ws, size_t ws_size,
                              hipStream_t stream) {
  const float* rgb = (const float*)d_in[0];
  const float* xin = (const float*)d_in[1];
  const float* Wr  = (const float*)d_in[2];
  const float* Wx  = (const float*)d_in[3];
  float* out = (float*)d_out;

  float* G    = (float*)d_ws;                       // 8 * 256 * 256
  float* ctxA = G + 8 * CD * CD;                    // 64 * 32 * 256
  float* S    = ctxA + 64 * HD * CD;                // 64 * 32 * 32

  hipMemsetAsync(G, 0, (size_t)8 * CD * CD * sizeof(float), stream);
  hipLaunchKernelGGL(gram_kernel, dim3(256),  dim3(512), 0, stream, rgb, xin, G);
  hipLaunchKernelGGL(ctxa_kernel, dim3(256),  dim3(256), 0, stream, Wr, Wx, G, ctxA);
  hipLaunchKernelGGL(ctxb_kernel, dim3(64),   dim3(256), 0, stream, Wr, Wx, ctxA, S);
  hipLaunchKernelGGL(out_kernel,  dim3(4096), dim3(256), 0, stream, rgb, xin, S, out);
}

// Round 2
// 294.332 us; speedup vs baseline: 1.0099x; 1.0099x over previous
//
#include <hip/hip_runtime.h>

#define NTOK 16384
#define CD   256
#define NH   8
#define HD   32

typedef __attribute__((ext_vector_type(4))) float f32x4;
typedef __attribute__((ext_vector_type(8))) short s16x8;

__device__ __forceinline__ unsigned short f2bf(float x) {
  union { float f; unsigned u; } a; a.f = x;
  unsigned r = a.u + 0x7fffu + ((a.u >> 16) & 1u);
  return (unsigned short)(r >> 16);
}
__device__ __forceinline__ float bf2f(unsigned short b) {
  union { unsigned u; float f; } a; a.u = ((unsigned)b) << 16;
  return a.f;
}

// ---------------------------------------------------------------------------
// Kernel 1: per-(stream,batch) Gram matrices  G = inp^T inp  [256x256] f32.
// 256 blocks = 8 matrices x 32 chunks of 512 rows. 512 threads (8 waves).
// f32 -> bf16 hi+lo split; accumulate hi^T hi + lo^T hi + hi^T lo via MFMA.
// ATOMIC=false: each block stores its partial to Gout + bid*64K (no atomics);
// ATOMIC=true : legacy fallback, atomicAdd into Gout + mat*64K.
// ---------------------------------------------------------------------------
template <bool ATOMIC>
__global__ __launch_bounds__(512) void gram_kernel(
    const float* __restrict__ rgb, const float* __restrict__ xin,
    float* __restrict__ Gout)
{
  __shared__ unsigned short lds[2][CD * 128];

  const int bid   = blockIdx.x;
  const int mat   = bid >> 5;            // 0..7 : s*4 + b
  const int chunk = bid & 31;
  const float* __restrict__ src =
      (mat < 4 ? rgb : xin) + (size_t)(mat & 3) * (NTOK * CD) + (size_t)chunk * 512 * CD;
  float* __restrict__ G =
      Gout + (ATOMIC ? (size_t)mat : (size_t)bid) * (CD * CD);

  const int t    = threadIdx.x;
  const int lane = t & 63;
  const int wv   = t >> 6;               // wave 0..7
  const int wr   = wv >> 2;              // M block (0..1) -> rows 128*wr
  const int wc   = wv & 3;               // N block (0..3) -> cols 64*wc
  const int cm   = lane & 15;
  const int qq   = lane >> 4;

  f32x4 acc[8][4];
#pragma unroll
  for (int i = 0; i < 8; ++i)
#pragma unroll
    for (int j = 0; j < 4; ++j) acc[i][j] = (f32x4){0.f, 0.f, 0.f, 0.f};

  f32x4 v[8];

  auto issue_loads = [&](int step) {
    const f32x4* p = (const f32x4*)(src + (size_t)step * 64 * CD);
#pragma unroll
    for (int i = 0; i < 8; ++i)
      v[i] = p[(wv * 8 + i) * (CD / 4) + lane];   // row wv*8+i, cols lane*4..+3
  };

  auto stage = [&](int buf) {
#pragma unroll
    for (int j = 0; j < 4; ++j) {
      const int c = lane * 4 + j;
      const int s = (c ^ (c >> 3)) & 7;
      s16x8 hi8, lo8;
#pragma unroll
      for (int i = 0; i < 8; ++i) {
        float x = v[i][j];
        unsigned short hb = f2bf(x);
        unsigned short lb = f2bf(x - bf2f(hb));
        hi8[i] = (short)hb;
        lo8[i] = (short)lb;
      }
      unsigned short* base = &lds[buf][c * 128];
      const int off = ((wv ^ s) & 7) * 8;
      *(s16x8*)(base + off)      = hi8;   // octet o = wv      (hi half, k 0..63)
      *(s16x8*)(base + off + 64) = lo8;   // octet o = 8 + wv  (lo half, k 64..127)
    }
  };

  auto compute = [&](int buf) {
    const unsigned short* L = lds[buf];
    const int OA[6] = {0, 4, 8, 12, 0, 4};   // ks 0,1: hi.hi ; 2,3: lo.hi ; 4,5: hi.lo
    const int OB[6] = {0, 4, 0, 4, 8, 12};
#pragma unroll
    for (int ks = 0; ks < 6; ++ks) {
      s16x8 af[8], bfr[4];
#pragma unroll
      for (int mt = 0; mt < 8; ++mt) {
        const int c = wr * 128 + mt * 16 + cm;
        const int s = (c ^ (c >> 3)) & 7;
        const int o = OA[ks] + qq;
        const int slot = (o & 8) | ((o ^ s) & 7);
        af[mt] = *(const s16x8*)&L[c * 128 + slot * 8];
      }
#pragma unroll
      for (int nt = 0; nt < 4; ++nt) {
        const int c = wc * 64 + nt * 16 + cm;
        const int s = (c ^ (c >> 3)) & 7;
        const int o = OB[ks] + qq;
        const int slot = (o & 8) | ((o ^ s) & 7);
        bfr[nt] = *(const s16x8*)&L[c * 128 + slot * 8];
      }
#pragma unroll
      for (int mt = 0; mt < 8; ++mt)
#pragma unroll
        for (int nt = 0; nt < 4; ++nt)
          acc[mt][nt] = __builtin_amdgcn_mfma_f32_16x16x32_bf16(
              af[mt], bfr[nt], acc[mt][nt], 0, 0, 0);
    }
  };

  issue_loads(0);
  stage(0);
  __syncthreads();
#pragma unroll 2
  for (int step = 0; step < 8; ++step) {
    const int cur = step & 1;
    if (step + 1 < 8) issue_loads(step + 1);
    compute(cur);
    if (step + 1 < 8) {
      stage(cur ^ 1);
      __syncthreads();
    }
  }

#pragma unroll
  for (int mt = 0; mt < 8; ++mt)
#pragma unroll
    for (int nt = 0; nt < 4; ++nt)
#pragma unroll
      for (int r = 0; r < 4; ++r) {
        const int row = wr * 128 + mt * 16 + qq * 4 + r;
        const int col = wc * 64 + nt * 16 + cm;
        if (ATOMIC)
          atomicAdd(&G[row * CD + col], acc[mt][nt][r]);
        else
          G[row * CD + col] = acc[mt][nt][r];
      }
}

// ---------------------------------------------------------------------------
// Kernel 1b: reduce the 32 per-chunk partials per matrix.  G = sum_c Gpart.
// grid 512 x 256 threads; one f32x4 per thread; fully coalesced.
// ---------------------------------------------------------------------------
__global__ __launch_bounds__(256) void greduce_kernel(
    const float* __restrict__ Gpart, float* __restrict__ G)
{
  const int g      = blockIdx.x * 256 + threadIdx.x;  // float4 index, 131072 total
  const int mat    = g >> 14;                          // 16384 float4 per matrix
  const int within = g & 16383;
  const f32x4* __restrict__ base =
      (const f32x4*)Gpart + (size_t)(mat * 32) * 16384 + within;
  f32x4 acc = (f32x4){0.f, 0.f, 0.f, 0.f};
#pragma unroll
  for (int c = 0; c < 32; ++c) acc += base[(size_t)c * 16384];
  ((f32x4*)G)[g] = acc;
}

// ---------------------------------------------------------------------------
// Kernel 2: ctxA = Wk_h @ G   [32 x 256] per (s,b,h); f32 VALU.
// grid 256 = (s*4+b)*32 + h*4 + cq ; block 256.
// ---------------------------------------------------------------------------
__global__ __launch_bounds__(256) void ctxa_kernel(
    const float* __restrict__ Wkv_rgb, const float* __restrict__ Wkv_x,
    const float* __restrict__ G, float* __restrict__ ctxA)
{
  const int bid = blockIdx.x;
  const int cq  = bid & 3;
  const int h   = (bid >> 2) & 7;
  const int mat = bid >> 5;              // s*4+b
  const int s   = mat >> 2;
  const int t   = threadIdx.x;
  const int d   = t >> 3;                // 0..31
  const int sub = t & 7;                 // 8 cols of 8

  const float* __restrict__ W  = (s == 0 ? Wkv_rgb : Wkv_x);
  const float* __restrict__ wk = W + (size_t)(h * HD + d) * CD;
  const float* __restrict__ g  = G + (size_t)mat * (CD * CD) + cq * 64 + sub * 8;

  f32x4 a0 = (f32x4){0.f,0.f,0.f,0.f}, a1 = (f32x4){0.f,0.f,0.f,0.f};
  for (int c = 0; c < CD; ++c) {
    const float w = wk[c];
    const f32x4* gr = (const f32x4*)(g + (size_t)c * CD);
    a0 += gr[0] * w;
    a1 += gr[1] * w;
  }
  float* outp = ctxA + ((size_t)(mat * NH + h) * HD + d) * CD + cq * 64 + sub * 8;
  *(f32x4*)outp       = a0;
  *(f32x4*)(outp + 4) = a1;
}

// ---------------------------------------------------------------------------
// Kernel 3: ctx = scale * ctxA @ Wv_h^T  [32 x 32], softmax over rows (d).
// grid 64 = mat*8 + h ; block 256.
// ---------------------------------------------------------------------------
__global__ __launch_bounds__(256) void ctxb_kernel(
    const float* __restrict__ Wkv_rgb, const float* __restrict__ Wkv_x,
    const float* __restrict__ ctxA, float* __restrict__ S)
{
  const int bid = blockIdx.x;            // mat*8 + h
  const int h   = bid & 7;
  const int mat = bid >> 3;
  const int s   = mat >> 2;
  const int t   = threadIdx.x;
  const int d   = t >> 3;                // 0..31
  const int eg  = t & 7;                 // 4 e's each

  __shared__ float sl[32 * 33];

  const float* __restrict__ W = (s == 0 ? Wkv_rgb : Wkv_x);
  const float* __restrict__ a = ctxA + ((size_t)bid * HD + d) * CD;

  float acc[4] = {0.f, 0.f, 0.f, 0.f};
  for (int c = 0; c < CD; ++c) {
    const float av = a[c];
#pragma unroll
    for (int j = 0; j < 4; ++j)
      acc[j] += av * W[(size_t)(CD + h * HD + eg * 4 + j) * CD + c];
  }
  const float scale = 0.17677669529663687f;   // 32^-0.5
#pragma unroll
  for (int j = 0; j < 4; ++j) sl[d * 33 + eg * 4 + j] = acc[j] * scale;
  __syncthreads();

  if (t < 32) {
    const int e = t;
    float m = -1e30f;
#pragma unroll
    for (int dd = 0; dd < 32; ++dd) m = fmaxf(m, sl[dd * 33 + e]);
    float ex[32];
    float sum = 0.f;
#pragma unroll
    for (int dd = 0; dd < 32; ++dd) { ex[dd] = __expf(sl[dd * 33 + e] - m); sum += ex[dd]; }
    const float inv = 1.f / sum;
    float* outp = S + (size_t)bid * (HD * HD);
#pragma unroll
    for (int dd = 0; dd < 32; ++dd) outp[dd * HD + e] = ex[dd] * inv;
  }
}

// ---------------------------------------------------------------------------
// Kernel 4: out_s = q_s @ blockdiag(S_{1-s})  — memory-bound bf16 MFMA pass.
// grid 4096 = ((s*4+b)*8 + h)*64 + nc ; block 256 (4 waves), 256 rows/block.
// ---------------------------------------------------------------------------
__global__ __launch_bounds__(256) void out_kernel(
    const float* __restrict__ rgb, const float* __restrict__ xin,
    const float* __restrict__ S, float* __restrict__ out)
{
  const int bid = blockIdx.x;
  const int nc  = bid & 63;
  const int h   = (bid >> 6) & 7;
  const int mat = bid >> 9;              // s*4 + b
  const int s   = mat >> 2;
  const int b   = mat & 3;

  const int t    = threadIdx.x;
  const int lane = t & 63;
  const int wv   = t >> 6;               // 0..3
  const int cm   = lane & 15;
  const int qq   = lane >> 4;

  const float* __restrict__ src = (s == 0 ? rgb : xin) + (size_t)b * NTOK * CD;
  float* __restrict__ dst = out + (size_t)s * (4ull * NTOK * CD) + (size_t)b * NTOK * CD;
  const float* __restrict__ sm =
      S + (size_t)(((1 - s) * 4 + b) * NH + h) * (HD * HD);

  // B fragments: ctx of the other stream, K=32, two 16-col tiles
  s16x8 bf0, bf1;
#pragma unroll
  for (int j = 0; j < 8; ++j) {
    const int k = qq * 8 + j;
    bf0[j] = (short)f2bf(sm[k * HD + cm]);
    bf1[j] = (short)f2bf(sm[k * HD + 16 + cm]);
  }

#pragma unroll
  for (int it = 0; it < 4; ++it) {
    const int row0 = nc * 256 + wv * 64 + it * 16;
    const float* qrow = src + (size_t)(row0 + cm) * CD + h * HD + qq * 8;
    const f32x4 q0 = *(const f32x4*)qrow;
    const f32x4 q1 = *(const f32x4*)(qrow + 4);
    s16x8 af;
#pragma unroll
    for (int j = 0; j < 4; ++j) {
      af[j]     = (short)f2bf(q0[j]);
      af[4 + j] = (short)f2bf(q1[j]);
    }
    f32x4 acc0 = (f32x4){0.f,0.f,0.f,0.f};
    f32x4 acc1 = (f32x4){0.f,0.f,0.f,0.f};
    acc0 = __builtin_amdgcn_mfma_f32_16x16x32_bf16(af, bf0, acc0, 0, 0, 0);
    acc1 = __builtin_amdgcn_mfma_f32_16x16x32_bf16(af, bf1, acc1, 0, 0, 0);
#pragma unroll
    for (int r = 0; r < 4; ++r) {
      const int row = row0 + qq * 4 + r;
      dst[(size_t)row * CD + h * HD + cm]      = acc0[r];
      dst[(size_t)row * CD + h * HD + 16 + cm] = acc1[r];
    }
  }
}

// ---------------------------------------------------------------------------
extern "C" void kernel_launch(void* const* d_in, const int* in_sizes, int n_in,
                              void* d_out, int out_size, void* d_ws, size_t ws_size,
                              hipStream_t stream) {
  const float* rgb = (const float*)d_in[0];
  const float* xin = (const float*)d_in[1];
  const float* Wr  = (const float*)d_in[2];
  const float* Wx  = (const float*)d_in[3];
  float* out = (float*)d_out;

  const size_t nGpart = (size_t)256 * CD * CD;      // 16.7M floats, 67 MB
  const size_t nG     = (size_t)8 * CD * CD;
  const size_t nCtxA  = (size_t)64 * HD * CD;
  const size_t nS     = (size_t)64 * HD * HD;
  const size_t need_partial = (nGpart + nG + nCtxA + nS) * sizeof(float);

  if (ws_size >= need_partial) {
    // fast path: non-atomic partial stores + BW-bound reduce
    float* Gpart = (float*)d_ws;
    float* G     = Gpart + nGpart;
    float* ctxA  = G + nG;
    float* S     = ctxA + nCtxA;

    hipLaunchKernelGGL((gram_kernel<false>), dim3(256), dim3(512), 0, stream, rgb, xin, Gpart);
    hipLaunchKernelGGL(greduce_kernel, dim3(512),  dim3(256), 0, stream, Gpart, G);
    hipLaunchKernelGGL(ctxa_kernel,    dim3(256),  dim3(256), 0, stream, Wr, Wx, G, ctxA);
    hipLaunchKernelGGL(ctxb_kernel,    dim3(64),   dim3(256), 0, stream, Wr, Wx, ctxA, S);
    hipLaunchKernelGGL(out_kernel,     dim3(4096), dim3(256), 0, stream, rgb, xin, S, out);
  } else {
    // fallback: atomic accumulation (verified round-1 path)
    float* G    = (float*)d_ws;
    float* ctxA = G + nG;
    float* S    = ctxA + nCtxA;

    hipMemsetAsync(G, 0, nG * sizeof(float), stream);
    hipLaunchKernelGGL((gram_kernel<true>), dim3(256), dim3(512), 0, stream, rgb, xin, G);
    hipLaunchKernelGGL(ctxa_kernel,    dim3(256),  dim3(256), 0, stream, Wr, Wx, G, ctxA);
    hipLaunchKernelGGL(ctxb_kernel,    dim3(64),   dim3(256), 0, stream, Wr, Wx, ctxA, S);
    hipLaunchKernelGGL(out_kernel,     dim3(4096), dim3(256), 0, stream, rgb, xin, S, out);
  }
}

// Round 4
// 133.497 us; speedup vs baseline: 2.2266x; 2.2048x over previous
//
#include <hip/hip_runtime.h>

#define NTOK 16384
#define CD   256
#define NH   8
#define HD   32
#define SCALE 0.17677669529663687f

typedef float    f32x4 __attribute__((ext_vector_type(4)));
typedef _Float16 f16x8 __attribute__((ext_vector_type(8)));
typedef _Float16 f16x4 __attribute__((ext_vector_type(4)));

__device__ __forceinline__ int a_addr(int n, int c) {
  return n * 256 + ((((c >> 3) ^ (n & 7)) << 3) | (c & 7));
}

template <bool ATOMIC>
__global__ __launch_bounds__(512, 2) void kvctx_kernel(
    const float* __restrict__ rgb, const float* __restrict__ xin,
    const float* __restrict__ Wr, const float* __restrict__ Wx,
    float* __restrict__ Mpart)
{
  __shared__ __align__(16) _Float16 Ah[2][32 * 256];
  __shared__ __align__(16) _Float16 KVl[8][64 * 40];

  const int bid   = blockIdx.x;
  const int mat   = bid >> 5;
  const int chunk = bid & 31;
  const int s     = mat >> 2;
  const float* __restrict__ A =
      (s == 0 ? rgb : xin) + (size_t)(mat & 3) * (NTOK * CD) + (size_t)chunk * 512 * CD;
  const float* __restrict__ W = (s == 0 ? Wr : Wx);

  const int t    = threadIdx.x;
  const int lane = t & 63;
  const int h    = t >> 6;
  const int cm   = lane & 15;
  const int qq   = lane >> 4;

  f32x4 v[4];
  auto issue_loads = [&](int sl) {
#pragma unroll
    for (int i = 0; i < 4; ++i)
      v[i] = *(const f32x4*)(A + (size_t)(sl * 32 + i * 8 + h) * CD + lane * 4);
  };
  auto stage = [&](int buf) {
#pragma unroll
    for (int i = 0; i < 4; ++i) {
      const int n = i * 8 + h;
      const int c = lane * 4;
      f16x4 p;
#pragma unroll
      for (int j = 0; j < 4; ++j) p[j] = (_Float16)v[i][j];
      *(f16x4*)&Ah[buf][a_addr(n, c)] = p;
    }
  };

  issue_loads(0);
  f16x8 wfrag[4][8];
#pragma unroll
  for (int jt = 0; jt < 4; ++jt) {
    const int wrow = (jt < 2) ? (h * HD + jt * 16 + cm)
                              : (CD + h * HD + (jt - 2) * 16 + cm);
    const float* wp = W + (size_t)wrow * CD;
#pragma unroll
    for (int ct = 0; ct < 8; ++ct) {
      f32x4 w0 = *(const f32x4*)(wp + ct * 32 + qq * 8);
      f32x4 w1 = *(const f32x4*)(wp + ct * 32 + qq * 8 + 4);
      f16x8 f;
#pragma unroll
      for (int j = 0; j < 4; ++j) { f[j] = (_Float16)w0[j]; f[4 + j] = (_Float16)w1[j]; }
      wfrag[jt][ct] = f;
    }
  }
  stage(0);
  __syncthreads();

  f32x4 ctx[2][2];
#pragma unroll
  for (int i = 0; i < 2; ++i)
#pragma unroll
    for (int j = 0; j < 2; ++j) ctx[i][j] = (f32x4){0.f, 0.f, 0.f, 0.f};

  _Float16* KW = KVl[h];

#pragma unroll 1
  for (int sl = 0; sl < 16; ++sl) {
    const int cur = sl & 1;
    if (sl < 15) issue_loads(sl + 1);

    f32x4 kv[2][4];
#pragma unroll
    for (int nt = 0; nt < 2; ++nt)
#pragma unroll
      for (int jt = 0; jt < 4; ++jt) kv[nt][jt] = (f32x4){0.f, 0.f, 0.f, 0.f};
#pragma unroll
    for (int ct = 0; ct < 8; ++ct) {
      f16x8 ah[2];
#pragma unroll
      for (int nt = 0; nt < 2; ++nt) {
        const int row = nt * 16 + cm;
        const int ad  = row * 256 + (((ct * 4 + qq) ^ (row & 7)) << 3);
        ah[nt] = *(const f16x8*)&Ah[cur][ad];
      }
#pragma unroll
      for (int nt = 0; nt < 2; ++nt)
#pragma unroll
        for (int jt = 0; jt < 4; ++jt)
          kv[nt][jt] = __builtin_amdgcn_mfma_f32_16x16x32_f16(ah[nt], wfrag[jt][ct], kv[nt][jt], 0, 0, 0);
    }

#pragma unroll
    for (int nt = 0; nt < 2; ++nt)
#pragma unroll
      for (int jt = 0; jt < 4; ++jt) {
        const int jj = jt * 16 + cm;
        const int ad = jj * 40 + nt * 16 + qq * 4;
        f16x4 p;
#pragma unroll
        for (int r = 0; r < 4; ++r) p[r] = (_Float16)kv[nt][jt][r];
        *(f16x4*)&KW[ad] = p;
      }

    f16x8 kf[2], vf[2];
#pragma unroll
    for (int dt = 0; dt < 2; ++dt)
      kf[dt] = *(const f16x8*)&KW[(dt * 16 + cm) * 40 + qq * 8];
#pragma unroll
    for (int et = 0; et < 2; ++et)
      vf[et] = *(const f16x8*)&KW[(32 + et * 16 + cm) * 40 + qq * 8];
#pragma unroll
    for (int dt = 0; dt < 2; ++dt)
#pragma unroll
      for (int et = 0; et < 2; ++et)
        ctx[dt][et] = __builtin_amdgcn_mfma_f32_16x16x32_f16(kf[dt], vf[et], ctx[dt][et], 0, 0, 0);

    if (sl < 15) {
      stage(cur ^ 1);
      __syncthreads();
    }
  }

  float* base = Mpart + ((size_t)((ATOMIC ? mat : bid) * NH + h)) * 1024;
#pragma unroll
  for (int dt = 0; dt < 2; ++dt)
#pragma unroll
    for (int et = 0; et < 2; ++et)
#pragma unroll
      for (int r = 0; r < 4; ++r) {
        const int d = dt * 16 + qq * 4 + r;
        const int e = et * 16 + cm;
        if (ATOMIC) atomicAdd(&base[d * 32 + e], ctx[dt][et][r]);
        else        base[d * 32 + e] = ctx[dt][et][r];
      }
}

__global__ __launch_bounds__(256) void corr_kernel(
    const float* __restrict__ Wr, const float* __restrict__ Wx,
    float* __restrict__ Corr)
{
  const int bid = blockIdx.x;
  const int s   = bid >> 3;
  const int h   = bid & 7;
  const float* __restrict__ W = (s == 0 ? Wr : Wx);
  const int t  = threadIdx.x;
  const int d  = t >> 3;
  const int eg = t & 7;

  const float* wk = W + (size_t)(h * HD + d) * CD;
  float acc[4] = {0.f, 0.f, 0.f, 0.f};
  for (int cq = 0; cq < 64; ++cq) {
    f32x4 k4 = *(const f32x4*)(wk + cq * 4);
    f32x4 kh4;
#pragma unroll
    for (int j = 0; j < 4; ++j) kh4[j] = (float)(_Float16)k4[j];
#pragma unroll
    for (int j = 0; j < 4; ++j) {
      const int e = eg * 4 + j;
      f32x4 v4 = *(const f32x4*)(W + (size_t)(CD + h * HD + e) * CD + cq * 4);
      f32x4 vh4;
#pragma unroll
      for (int r = 0; r < 4; ++r) vh4[r] = (float)(_Float16)v4[r];
      f32x4 p = k4 * v4 - kh4 * vh4;
      acc[j] += p[0] + p[1] + p[2] + p[3];
    }
  }
#pragma unroll
  for (int j = 0; j < 4; ++j)
    Corr[(size_t)bid * 1024 + d * 32 + eg * 4 + j] = 16384.f * acc[j];
}

template <int NPART>
__global__ __launch_bounds__(256) void redsm_kernel(
    const float* __restrict__ Mpart, const float* __restrict__ Corr,
    float* __restrict__ S)
{
  __shared__ float sl[32 * 33];
  const int bid = blockIdx.x;
  const int h   = bid & 7;
  const int mat = bid >> 3;
  const int s   = mat >> 2;
  const int t   = threadIdx.x;
  const int flat = t * 4;

  f32x4 acc = *(const f32x4*)(Corr + (size_t)(s * 8 + h) * 1024 + flat);
  const float* base = Mpart + ((size_t)(mat * NPART) * NH + h) * 1024 + flat;
#pragma unroll
  for (int p = 0; p < NPART; ++p) acc += *(const f32x4*)(base + (size_t)p * NH * 1024);

  const int d = flat >> 5, e = flat & 31;
#pragma unroll
  for (int j = 0; j < 4; ++j) sl[d * 33 + e + j] = acc[j] * SCALE;
  __syncthreads();

  if (t < 32) {
    const int ee = t;
    float m = -1e30f;
#pragma unroll
    for (int dd = 0; dd < 32; ++dd) m = fmaxf(m, sl[dd * 33 + ee]);
    float ex[32];
    float sum = 0.f;
#pragma unroll
    for (int dd = 0; dd < 32; ++dd) { ex[dd] = __expf(sl[dd * 33 + ee] - m); sum += ex[dd]; }
    const float inv = 1.f / sum;
    float* outp = S + (size_t)bid * (HD * HD);
#pragma unroll
    for (int dd = 0; dd < 32; ++dd) outp[dd * HD + ee] = ex[dd] * inv;
  }
}

__global__ __launch_bounds__(256) void out_kernel(
    const float* __restrict__ rgb, const float* __restrict__ xin,
    const float* __restrict__ Sm, float* __restrict__ out)
{
  const int bid  = blockIdx.x;
  const int t    = threadIdx.x;
  const int lane = t & 63;
  const int wv   = t >> 6;
  const int cm   = lane & 15;
  const int qq   = lane >> 4;

  const int grow0 = bid * 128;
  const int s     = grow0 >> 16;
  const int b     = (grow0 >> 14) & 3;
  const int lrow0 = grow0 & 16383;

  const float* __restrict__ src = (s == 0 ? rgb : xin) + (size_t)b * NTOK * CD;
  float* __restrict__ dst = out + (size_t)s * (4ull * NTOK * CD) + (size_t)b * NTOK * CD;

  f16x8 bf[8][2];
#pragma unroll
  for (int h = 0; h < 8; ++h) {
    const float* sm = Sm + (size_t)(((1 - s) * 4 + b) * NH + h) * 1024;
#pragma unroll
    for (int j = 0; j < 8; ++j) {
      const int k = qq * 8 + j;
      bf[h][0][j] = (_Float16)sm[k * HD + cm];
      bf[h][1][j] = (_Float16)sm[k * HD + 16 + cm];
    }
  }

#pragma unroll
  for (int it = 0; it < 2; ++it) {
    const int row0 = lrow0 + wv * 32 + it * 16;
    const float* qrow = src + (size_t)(row0 + cm) * CD;
#pragma unroll
    for (int h = 0; h < 8; ++h) {
      f32x4 q0 = *(const f32x4*)(qrow + h * HD + qq * 8);
      f32x4 q1 = *(const f32x4*)(qrow + h * HD + qq * 8 + 4);
      f16x8 af;
#pragma unroll
      for (int j = 0; j < 4; ++j) { af[j] = (_Float16)q0[j]; af[4 + j] = (_Float16)q1[j]; }
      f32x4 a0 = (f32x4){0.f, 0.f, 0.f, 0.f};
      f32x4 a1 = (f32x4){0.f, 0.f, 0.f, 0.f};
      a0 = __builtin_amdgcn_mfma_f32_16x16x32_f16(af, bf[h][0], a0, 0, 0, 0);
      a1 = __builtin_amdgcn_mfma_f32_16x16x32_f16(af, bf[h][1], a1, 0, 0, 0);
#pragma unroll
      for (int r = 0; r < 4; ++r) {
        const int row = row0 + qq * 4 + r;
        dst[(size_t)row * CD + h * HD + cm]      = a0[r];
        dst[(size_t)row * CD + h * HD + 16 + cm] = a1[r];
      }
    }
  }
}

extern "C" void kernel_launch(void* const* d_in, const int* in_sizes, int n_in,
                              void* d_out, int out_size, void* d_ws, size_t ws_size,
                              hipStream_t stream) {
  const float* rgb = (const float*)d_in[0];
  const float* xin = (const float*)d_in[1];
  const float* Wr  = (const float*)d_in[2];
  const float* Wx  = (const float*)d_in[3];
  float* out = (float*)d_out;

  float* S     = (float*)d_ws;
  float* Corr  = S + 64 * 1024;
  float* Mpart = Corr + 16 * 1024;

  const size_t need_fast =
      (size_t)(64 * 1024 + 16 * 1024 + 256 * NH * 1024) * sizeof(float);

  hipLaunchKernelGGL(corr_kernel, dim3(16), dim3(256), 0, stream, Wr, Wx, Corr);
  if (ws_size >= need_fast) {
    hipLaunchKernelGGL((kvctx_kernel<false>), dim3(256), dim3(512), 0, stream,
                       rgb, xin, Wr, Wx, Mpart);
    hipLaunchKernelGGL((redsm_kernel<32>), dim3(64), dim3(256), 0, stream, Mpart, Corr, S);
  } else {
    hipMemsetAsync(Mpart, 0, (size_t)64 * 1024 * sizeof(float), stream);
    hipLaunchKernelGGL((kvctx_kernel<true>), dim3(256), dim3(512), 0, stream,
                       rgb, xin, Wr, Wx, Mpart);
    hipLaunchKernelGGL((redsm_kernel<1>), dim3(64), dim3(256), 0, stream, Mpart, Corr, S);
  }
  hipLaunchKernelGGL(out_kernel, dim3(1024), dim3(256), 0, stream, rgb, xin, S, out);
}

// Round 5
// 130.786 us; speedup vs baseline: 2.2727x; 1.0207x over previous
//
#include <hip/hip_runtime.h>

#define NTOK 16384
#define CD   256
#define NH   8
#define HD   32
#define SCALE 0.17677669529663687f

typedef float    f32x4 __attribute__((ext_vector_type(4)));
typedef _Float16 f16x8 __attribute__((ext_vector_type(8)));
typedef _Float16 f16x4 __attribute__((ext_vector_type(4)));

__device__ __forceinline__ int a_addr(int n, int c) {
  return n * 256 + ((((c >> 3) ^ (n & 7)) << 3) | (c & 7));
}

// ---------------------------------------------------------------------------
// Fused KV-projection + per-head context partials (fp16 MFMA).
//   ctx_h(b) = K_hᵀ V_h,  K = A Wkᵀ, V = A Wvᵀ
// Grid 256 = 8 mats x 32 chunks (512 rows). Block 512 = 8 waves, wave = head.
// Partials go to Mpart = d_out scratch (fully overwritten by out_kernel later).
// ---------------------------------------------------------------------------
__global__ __launch_bounds__(512, 2) void kvctx_kernel(
    const float* __restrict__ rgb, const float* __restrict__ xin,
    const float* __restrict__ Wr, const float* __restrict__ Wx,
    float* __restrict__ Mpart)
{
  __shared__ __align__(16) _Float16 Ah[2][32 * 256];
  __shared__ __align__(16) _Float16 KVl[8][64 * 40];

  const int bid   = blockIdx.x;
  const int mat   = bid >> 5;              // s*4 + b
  const int chunk = bid & 31;
  const int s     = mat >> 2;
  const float* __restrict__ A =
      (s == 0 ? rgb : xin) + (size_t)(mat & 3) * (NTOK * CD) + (size_t)chunk * 512 * CD;
  const float* __restrict__ W = (s == 0 ? Wr : Wx);

  const int t    = threadIdx.x;
  const int lane = t & 63;
  const int h    = t >> 6;                 // wave index = head
  const int cm   = lane & 15;
  const int qq   = lane >> 4;

  f32x4 v[4];
  auto issue_loads = [&](int sl) {
#pragma unroll
    for (int i = 0; i < 4; ++i)
      v[i] = *(const f32x4*)(A + (size_t)(sl * 32 + i * 8 + h) * CD + lane * 4);
  };
  auto stage = [&](int buf) {
#pragma unroll
    for (int i = 0; i < 4; ++i) {
      const int n = i * 8 + h;
      const int c = lane * 4;
      f16x4 p;
#pragma unroll
      for (int j = 0; j < 4; ++j) p[j] = (_Float16)v[i][j];
      *(f16x4*)&Ah[buf][a_addr(n, c)] = p;
    }
  };

  issue_loads(0);
  f16x8 wfrag[4][8];
#pragma unroll
  for (int jt = 0; jt < 4; ++jt) {
    const int wrow = (jt < 2) ? (h * HD + jt * 16 + cm)
                              : (CD + h * HD + (jt - 2) * 16 + cm);
    const float* wp = W + (size_t)wrow * CD;
#pragma unroll
    for (int ct = 0; ct < 8; ++ct) {
      f32x4 w0 = *(const f32x4*)(wp + ct * 32 + qq * 8);
      f32x4 w1 = *(const f32x4*)(wp + ct * 32 + qq * 8 + 4);
      f16x8 f;
#pragma unroll
      for (int j = 0; j < 4; ++j) { f[j] = (_Float16)w0[j]; f[4 + j] = (_Float16)w1[j]; }
      wfrag[jt][ct] = f;
    }
  }
  stage(0);
  __syncthreads();

  f32x4 ctx[2][2];
#pragma unroll
  for (int i = 0; i < 2; ++i)
#pragma unroll
    for (int j = 0; j < 2; ++j) ctx[i][j] = (f32x4){0.f, 0.f, 0.f, 0.f};

  _Float16* KW = KVl[h];

#pragma unroll 1
  for (int sl = 0; sl < 16; ++sl) {
    const int cur = sl & 1;
    if (sl < 15) issue_loads(sl + 1);

    // GEMM1: KV[32 n x 64 j] = A_slab x Wᵀ
    f32x4 kv[2][4];
#pragma unroll
    for (int nt = 0; nt < 2; ++nt)
#pragma unroll
      for (int jt = 0; jt < 4; ++jt) kv[nt][jt] = (f32x4){0.f, 0.f, 0.f, 0.f};
#pragma unroll
    for (int ct = 0; ct < 8; ++ct) {
      f16x8 ah[2];
#pragma unroll
      for (int nt = 0; nt < 2; ++nt) {
        const int row = nt * 16 + cm;
        const int ad  = row * 256 + (((ct * 4 + qq) ^ (row & 7)) << 3);
        ah[nt] = *(const f16x8*)&Ah[cur][ad];
      }
#pragma unroll
      for (int nt = 0; nt < 2; ++nt)
#pragma unroll
        for (int jt = 0; jt < 4; ++jt)
          kv[nt][jt] = __builtin_amdgcn_mfma_f32_16x16x32_f16(ah[nt], wfrag[jt][ct], kv[nt][jt], 0, 0, 0);
    }

    // KV -> wave-private LDS, [j][n] layout
#pragma unroll
    for (int nt = 0; nt < 2; ++nt)
#pragma unroll
      for (int jt = 0; jt < 4; ++jt) {
        const int jj = jt * 16 + cm;
        const int ad = jj * 40 + nt * 16 + qq * 4;
        f16x4 p;
#pragma unroll
        for (int r = 0; r < 4; ++r) p[r] = (_Float16)kv[nt][jt][r];
        *(f16x4*)&KW[ad] = p;
      }

    // GEMM2: ctx[d][e] += Σ_n K[n,d] V[n,e]
    f16x8 kf[2], vf[2];
#pragma unroll
    for (int dt = 0; dt < 2; ++dt)
      kf[dt] = *(const f16x8*)&KW[(dt * 16 + cm) * 40 + qq * 8];
#pragma unroll
    for (int et = 0; et < 2; ++et)
      vf[et] = *(const f16x8*)&KW[(32 + et * 16 + cm) * 40 + qq * 8];
#pragma unroll
    for (int dt = 0; dt < 2; ++dt)
#pragma unroll
      for (int et = 0; et < 2; ++et)
        ctx[dt][et] = __builtin_amdgcn_mfma_f32_16x16x32_f16(kf[dt], vf[et], ctx[dt][et], 0, 0, 0);

    if (sl < 15) {
      stage(cur ^ 1);
      __syncthreads();
    }
  }

  float* base = Mpart + ((size_t)(bid * NH + h)) * 1024;
#pragma unroll
  for (int dt = 0; dt < 2; ++dt)
#pragma unroll
    for (int et = 0; et < 2; ++et)
#pragma unroll
      for (int r = 0; r < 4; ++r) {
        const int d = dt * 16 + qq * 4 + r;
        const int e = et * 16 + cm;
        base[d * 32 + e] = ctx[dt][et][r];
      }
}

// ---------------------------------------------------------------------------
// Reduce 32 chunk partials + inline fp16-W compensation, scale, softmax over
// d (axis -2); emit S as f16 in MFMA B-fragment layout Sf[mat][h][e][d].
// Grid 64 = mat*8 + h ; block 256.
// Corr[d,e] = 16384 * (wk_d·wv_e − fp16(wk_d)·fp16(wv_e))  (G ≈ N·I term).
// ---------------------------------------------------------------------------
__global__ __launch_bounds__(256) void redsm_kernel(
    const float* __restrict__ Mpart,
    const float* __restrict__ Wr, const float* __restrict__ Wx,
    _Float16* __restrict__ Sf)
{
  __shared__ float sl[32 * 33];
  const int bid = blockIdx.x;              // mat*8 + h
  const int h   = bid & 7;
  const int mat = bid >> 3;
  const int s   = mat >> 2;
  const int t   = threadIdx.x;
  const int d   = t >> 3;                  // 0..31
  const int eg  = t & 7;                   // 4 e's

  // inline W-rounding compensation
  const float* __restrict__ W = (s == 0 ? Wr : Wx);
  const float* wk = W + (size_t)(h * HD + d) * CD;
  float cacc[4] = {0.f, 0.f, 0.f, 0.f};
  for (int cq = 0; cq < 64; ++cq) {
    f32x4 k4 = *(const f32x4*)(wk + cq * 4);
    f32x4 kh4;
#pragma unroll
    for (int j = 0; j < 4; ++j) kh4[j] = (float)(_Float16)k4[j];
#pragma unroll
    for (int j = 0; j < 4; ++j) {
      const int e = eg * 4 + j;
      f32x4 v4 = *(const f32x4*)(W + (size_t)(CD + h * HD + e) * CD + cq * 4);
      f32x4 vh4;
#pragma unroll
      for (int r = 0; r < 4; ++r) vh4[r] = (float)(_Float16)v4[r];
      f32x4 p = k4 * v4 - kh4 * vh4;
      cacc[j] += p[0] + p[1] + p[2] + p[3];
    }
  }

  const int flat = t * 4;                  // element [d][eg*4 .. +3]
  f32x4 acc;
#pragma unroll
  for (int j = 0; j < 4; ++j) acc[j] = 16384.f * cacc[j];
  const float* base = Mpart + ((size_t)(mat * 32) * NH + h) * 1024 + flat;
#pragma unroll
  for (int p = 0; p < 32; ++p) acc += *(const f32x4*)(base + (size_t)p * NH * 1024);

  const int e0 = flat & 31;
#pragma unroll
  for (int j = 0; j < 4; ++j) sl[d * 33 + e0 + j] = acc[j] * SCALE;
  __syncthreads();

  if (t < 32) {
    const int ee = t;
    float m = -1e30f;
#pragma unroll
    for (int dd = 0; dd < 32; ++dd) m = fmaxf(m, sl[dd * 33 + ee]);
    float ex[32];
    float sum = 0.f;
#pragma unroll
    for (int dd = 0; dd < 32; ++dd) { ex[dd] = __expf(sl[dd * 33 + ee] - m); sum += ex[dd]; }
    const float inv = 1.f / sum;
    _Float16* outp = Sf + (size_t)bid * 1024 + ee * 32;   // [e][d], d contiguous
#pragma unroll
    for (int dq = 0; dq < 4; ++dq) {
      f16x8 pk;
#pragma unroll
      for (int j = 0; j < 8; ++j) pk[j] = (_Float16)(ex[dq * 8 + j] * inv);
      *(f16x8*)(outp + dq * 8) = pk;
    }
  }
}

// ---------------------------------------------------------------------------
// out_s = q_s @ blockdiag(S_{1-s}) — all 8 heads per block, full-row I/O.
// Grid 1024 x 256 thr; block covers 128 rows. S read as f16 fragments.
// ---------------------------------------------------------------------------
__global__ __launch_bounds__(256) void out_kernel(
    const float* __restrict__ rgb, const float* __restrict__ xin,
    const _Float16* __restrict__ Sf, float* __restrict__ out)
{
  const int bid  = blockIdx.x;
  const int t    = threadIdx.x;
  const int lane = t & 63;
  const int wv   = t >> 6;
  const int cm   = lane & 15;
  const int qq   = lane >> 4;

  const int grow0 = bid * 128;
  const int s     = grow0 >> 16;
  const int b     = (grow0 >> 14) & 3;
  const int lrow0 = grow0 & 16383;

  const float* __restrict__ src = (s == 0 ? rgb : xin) + (size_t)b * NTOK * CD;
  float* __restrict__ dst = out + (size_t)s * (4ull * NTOK * CD) + (size_t)b * NTOK * CD;

  // S fragments for all 8 heads of the OTHER stream: b128 loads, frag-layout
  f16x8 bf[8][2];
#pragma unroll
  for (int h = 0; h < 8; ++h) {
    const _Float16* sm = Sf + (size_t)(((1 - s) * 4 + b) * NH + h) * 1024;
#pragma unroll
    for (int et = 0; et < 2; ++et)
      bf[h][et] = *(const f16x8*)&sm[(et * 16 + cm) * 32 + qq * 8];
  }

#pragma unroll
  for (int it = 0; it < 2; ++it) {
    const int row0 = lrow0 + wv * 32 + it * 16;
    const float* qrow = src + (size_t)(row0 + cm) * CD;
#pragma unroll
    for (int h = 0; h < 8; ++h) {
      f32x4 q0 = *(const f32x4*)(qrow + h * HD + qq * 8);
      f32x4 q1 = *(const f32x4*)(qrow + h * HD + qq * 8 + 4);
      f16x8 af;
#pragma unroll
      for (int j = 0; j < 4; ++j) { af[j] = (_Float16)q0[j]; af[4 + j] = (_Float16)q1[j]; }
      f32x4 a0 = (f32x4){0.f, 0.f, 0.f, 0.f};
      f32x4 a1 = (f32x4){0.f, 0.f, 0.f, 0.f};
      a0 = __builtin_amdgcn_mfma_f32_16x16x32_f16(af, bf[h][0], a0, 0, 0, 0);
      a1 = __builtin_amdgcn_mfma_f32_16x16x32_f16(af, bf[h][1], a1, 0, 0, 0);
#pragma unroll
      for (int r = 0; r < 4; ++r) {
        const int row = row0 + qq * 4 + r;
        dst[(size_t)row * CD + h * HD + cm]      = a0[r];
        dst[(size_t)row * CD + h * HD + 16 + cm] = a1[r];
      }
    }
  }
}

// ---------------------------------------------------------------------------
extern "C" void kernel_launch(void* const* d_in, const int* in_sizes, int n_in,
                              void* d_out, int out_size, void* d_ws, size_t ws_size,
                              hipStream_t stream) {
  const float* rgb = (const float*)d_in[0];
  const float* xin = (const float*)d_in[1];
  const float* Wr  = (const float*)d_in[2];
  const float* Wx  = (const float*)d_in[3];
  float* out = (float*)d_out;

  // Mpart (8.4 MB) lives in d_out scratch space: redsm consumes it before
  // out_kernel overwrites every element of d_out (stream-ordered, determin.).
  float*     Mpart = (float*)d_out;                 // 256*8*1024 floats
  _Float16*  Sf    = (_Float16*)d_ws;               // 64*1024 halfs = 128 KB

  hipLaunchKernelGGL(kvctx_kernel, dim3(256),  dim3(512), 0, stream,
                     rgb, xin, Wr, Wx, Mpart);
  hipLaunchKernelGGL(redsm_kernel, dim3(64),   dim3(256), 0, stream,
                     Mpart, Wr, Wx, Sf);
  hipLaunchKernelGGL(out_kernel,   dim3(1024), dim3(256), 0, stream,
                     rgb, xin, Sf, out);
}